// Round 1
// baseline (1024.547 us; speedup 1.0000x reference)
//
#include <hip/hip_runtime.h>

typedef float  f4     __attribute__((ext_vector_type(4)));
typedef float  f32x4  __attribute__((ext_vector_type(4)));
typedef short  short8 __attribute__((ext_vector_type(8)));
typedef __bf16 bf16x8 __attribute__((ext_vector_type(8)));

__device__ __forceinline__ unsigned short f2bf(float f) {
    unsigned int u = __builtin_bit_cast(unsigned int, f);
    u += 0x7FFFu + ((u >> 16) & 1u);
    return (unsigned short)(u >> 16);
}
__device__ __forceinline__ float bf2f(unsigned short h) {
    unsigned int u = ((unsigned int)h) << 16;
    return __builtin_bit_cast(float, u);
}

__device__ __forceinline__ f32x4 mfma_bf16(short8 a, short8 b, f32x4 c) {
    return __builtin_amdgcn_mfma_f32_16x16x32_bf16(
        __builtin_bit_cast(bf16x8, a), __builtin_bit_cast(bf16x8, b), c, 0, 0, 0);
}

struct Acc42 { f32x4 a[4][2]; float bia[2]; };

// 64x256x256 GEMM slice: this wave computes output n-tiles {2*wave, 2*wave+1}
// A: bf16 [64][264] tile in LDS at src_off (row stride 528 B)
// B: fp32 weight matrix (c_out, c_in) row-major in global (L2-hot), cvt to bf16
__device__ __forceinline__ Acc42 gemm64(char* sm, int src_off,
                                        const float* __restrict__ Wm,
                                        const float* __restrict__ bias,
                                        int wave, int g, int l15) {
    short8 bw[2][8];
    const int cout0 = 32 * wave + l15;
    #pragma unroll
    for (int n = 0; n < 2; ++n) {
        const float* wp = Wm + (cout0 + 16 * n) * 256 + g * 8;
        #pragma unroll
        for (int k = 0; k < 8; ++k) {
            f4 w0 = *(const f4*)(wp + k * 32);
            f4 w1 = *(const f4*)(wp + k * 32 + 4);
            short8 t;
            t[0] = (short)f2bf(w0[0]); t[1] = (short)f2bf(w0[1]);
            t[2] = (short)f2bf(w0[2]); t[3] = (short)f2bf(w0[3]);
            t[4] = (short)f2bf(w1[0]); t[5] = (short)f2bf(w1[1]);
            t[6] = (short)f2bf(w1[2]); t[7] = (short)f2bf(w1[3]);
            bw[n][k] = t;
        }
    }
    Acc42 r;
    f32x4 z = {0.f, 0.f, 0.f, 0.f};
    #pragma unroll
    for (int m = 0; m < 4; ++m) { r.a[m][0] = z; r.a[m][1] = z; }
    #pragma unroll
    for (int k = 0; k < 8; ++k) {
        #pragma unroll
        for (int m = 0; m < 4; ++m) {
            short8 am = *(const short8*)(sm + src_off + (16 * m + l15) * 528 + (k * 32 + g * 8) * 2);
            r.a[m][0] = mfma_bf16(am, bw[0][k], r.a[m][0]);
            r.a[m][1] = mfma_bf16(am, bw[1][k], r.a[m][1]);
        }
    }
    r.bia[0] = bias[cout0];
    r.bia[1] = bias[cout0 + 16];
    return r;
}

__global__ __launch_bounds__(512, 2) void pcaf_kernel(
    const float* __restrict__ y_lf, const float* __restrict__ y_hf,
    const float* __restrict__ g_lf, const float* __restrict__ b_lf,
    const float* __restrict__ g_hf, const float* __restrict__ b_hf,
    const float* __restrict__ Wq, const float* __restrict__ bq,
    const float* __restrict__ Wk, const float* __restrict__ bk,
    const float* __restrict__ Wv, const float* __restrict__ bv,
    const float* __restrict__ Wo, const float* __restrict__ bo,
    float* __restrict__ out)
{
    constexpr int C = 256, H = 256, W = 256, HW = H * W;
    constexpr int RS = 528;          // 264 bf16 per row
    constexpr int O_LNLF = 0;        // lnlf (t0-t2) -> K (t3-t4)
    constexpr int O_LNHF = 33792;    // lnhf (t0-t3) -> per-wave P chunks (t4)
    constexpr int O_HFQ  = 67584;    // raw hf (t0-t1) -> Q/O (t2-t5)
    constexpr int O_VT   = 101376;   // V^T [256][72] bf16, row stride 144 B (t1-t4)
    constexpr int O_GB   = 138240;   // g_lf|b_lf|g_hf|b_hf, 1024 floats (t0)
    __shared__ __align__(16) char sm[142336];

    const int tid  = threadIdx.x;
    const int wi   = blockIdx.x;
    const int bb   = wi >> 10;
    const int nh   = (wi >> 5) & 31;
    const int nw   = wi & 31;
    const long win_base = (long)bb * C * HW + (long)(nh * 8) * W + nw * 8;

    const int wave = tid >> 6;
    const int lane = tid & 63;
    const int g    = lane >> 4;
    const int l15  = lane & 15;

    // ---------------- t0a: stage gamma/beta + raw windows (fp32 -> bf16) ----
    if (tid < 256) {
        float* gbp = (float*)(sm + O_GB);
        gbp[tid]       = g_lf[tid];
        gbp[256 + tid] = b_lf[tid];
        gbp[512 + tid] = g_hf[tid];
        gbp[768 + tid] = b_hf[tid];
    }
    #pragma unroll
    for (int it = 0; it < 4; ++it) {
        int q2  = it * 512 + tid;        // 0..2047
        int c2  = q2 >> 4;               // channel pair index 0..127
        int ph  = (q2 >> 1) & 7;
        int pw4 = (q2 & 1) * 4;
        long go = win_base + (long)(2 * c2) * HW + ph * W + pw4;
        f4 l0 = *(const f4*)(y_lf + go);
        f4 l1 = *(const f4*)(y_lf + go + HW);
        f4 h0 = *(const f4*)(y_hf + go);
        f4 h1 = *(const f4*)(y_hf + go + HW);
        int tok0 = ph * 8 + pw4;
        #pragma unroll
        for (int j = 0; j < 4; ++j) {
            unsigned int lv = (unsigned int)f2bf(l0[j]) | ((unsigned int)f2bf(l1[j]) << 16);
            unsigned int hv = (unsigned int)f2bf(h0[j]) | ((unsigned int)f2bf(h1[j]) << 16);
            *(unsigned int*)(sm + O_LNLF + (tok0 + j) * RS + c2 * 4) = lv;
            *(unsigned int*)(sm + O_HFQ  + (tok0 + j) * RS + c2 * 4) = hv;
        }
    }
    __syncthreads();

    // ---------------- t0c: LayerNorm (lf in place; hf -> lnhf) --------------
    {
        const int t = tid >> 3, j = tid & 7;     // token, 32-channel chunk
        const float* gbp = (const float*)(sm + O_GB);
        // ---- lf (normalize in place) ----
        {
            short8 raw[4];
            float sum = 0.f, ss = 0.f;
            #pragma unroll
            for (int r = 0; r < 4; ++r) {
                raw[r] = *(const short8*)(sm + O_LNLF + t * RS + (j * 32 + r * 8) * 2);
                #pragma unroll
                for (int e = 0; e < 8; ++e) { float f = bf2f((unsigned short)raw[r][e]); sum += f; ss += f * f; }
            }
            sum += __shfl_xor(sum, 1); ss += __shfl_xor(ss, 1);
            sum += __shfl_xor(sum, 2); ss += __shfl_xor(ss, 2);
            sum += __shfl_xor(sum, 4); ss += __shfl_xor(ss, 4);
            float mean = sum * (1.f / 256.f);
            float rstd = rsqrtf(ss * (1.f / 256.f) - mean * mean + 1e-5f);
            #pragma unroll
            for (int r = 0; r < 4; ++r) {
                short8 o;
                #pragma unroll
                for (int e = 0; e < 8; ++e) {
                    int c = j * 32 + r * 8 + e;
                    float f = (bf2f((unsigned short)raw[r][e]) - mean) * rstd * gbp[c] + gbp[256 + c];
                    o[e] = (short)f2bf(f);
                }
                *(short8*)(sm + O_LNLF + t * RS + (j * 32 + r * 8) * 2) = o;
            }
        }
        // ---- hf (raw kept; normalized copy -> lnhf) ----
        {
            short8 raw[4];
            float sum = 0.f, ss = 0.f;
            #pragma unroll
            for (int r = 0; r < 4; ++r) {
                raw[r] = *(const short8*)(sm + O_HFQ + t * RS + (j * 32 + r * 8) * 2);
                #pragma unroll
                for (int e = 0; e < 8; ++e) { float f = bf2f((unsigned short)raw[r][e]); sum += f; ss += f * f; }
            }
            sum += __shfl_xor(sum, 1); ss += __shfl_xor(ss, 1);
            sum += __shfl_xor(sum, 2); ss += __shfl_xor(ss, 2);
            sum += __shfl_xor(sum, 4); ss += __shfl_xor(ss, 4);
            float mean = sum * (1.f / 256.f);
            float rstd = rsqrtf(ss * (1.f / 256.f) - mean * mean + 1e-5f);
            #pragma unroll
            for (int r = 0; r < 4; ++r) {
                short8 o;
                #pragma unroll
                for (int e = 0; e < 8; ++e) {
                    int c = j * 32 + r * 8 + e;
                    float f = (bf2f((unsigned short)raw[r][e]) - mean) * rstd * gbp[512 + c] + gbp[768 + c];
                    o[e] = (short)f2bf(f);
                }
                *(short8*)(sm + O_LNHF + t * RS + (j * 32 + r * 8) * 2) = o;
            }
        }
    }
    __syncthreads();

    // ---------------- t1: residual -> regs, V = hf @ Wv^T + bv -> V^T -------
    float res[4][2][4];
    #pragma unroll
    for (int m = 0; m < 4; ++m)
        #pragma unroll
        for (int n = 0; n < 2; ++n) {
            int col = 32 * wave + 16 * n + l15;
            #pragma unroll
            for (int i = 0; i < 4; ++i)
                res[m][n][i] = bf2f(*(const unsigned short*)(sm + O_HFQ + (16 * m + 4 * g + i) * RS + col * 2));
        }
    {
        Acc42 v = gemm64(sm, O_HFQ, Wv, bv, wave, g, l15);
        #pragma unroll
        for (int m = 0; m < 4; ++m)
            #pragma unroll
            for (int n = 0; n < 2; ++n) {
                int cout = 32 * wave + 16 * n + l15;
                unsigned int p0 = (unsigned int)f2bf(v.a[m][n][0] + v.bia[n]) |
                                  ((unsigned int)f2bf(v.a[m][n][1] + v.bia[n]) << 16);
                unsigned int p1 = (unsigned int)f2bf(v.a[m][n][2] + v.bia[n]) |
                                  ((unsigned int)f2bf(v.a[m][n][3] + v.bia[n]) << 16);
                char* p = sm + O_VT + cout * 144 + (16 * m + 4 * g) * 2;
                *(unsigned int*)(p)     = p0;
                *(unsigned int*)(p + 4) = p1;
            }
    }
    __syncthreads();

    // ---------------- t2: Q = LN(lf) @ Wq^T + bq, scaled -> (hf region) -----
    {
        Acc42 q = gemm64(sm, O_LNLF, Wq, bq, wave, g, l15);
        const float SCALE = 0.17677669529663687f;   // 1/sqrt(32)
        #pragma unroll
        for (int m = 0; m < 4; ++m)
            #pragma unroll
            for (int n = 0; n < 2; ++n) {
                int cout = 32 * wave + 16 * n + l15;
                #pragma unroll
                for (int i = 0; i < 4; ++i) {
                    float val = (q.a[m][n][i] + q.bia[n]) * SCALE;
                    *(unsigned short*)(sm + O_HFQ + (16 * m + 4 * g + i) * RS + cout * 2) = f2bf(val);
                }
            }
    }
    __syncthreads();

    // ---------------- t3: K = LN(hf) @ Wk^T + bk -> (lnlf region) -----------
    {
        Acc42 kk = gemm64(sm, O_LNHF, Wk, bk, wave, g, l15);
        #pragma unroll
        for (int m = 0; m < 4; ++m)
            #pragma unroll
            for (int n = 0; n < 2; ++n) {
                int cout = 32 * wave + 16 * n + l15;
                #pragma unroll
                for (int i = 0; i < 4; ++i)
                    *(unsigned short*)(sm + O_LNLF + (16 * m + 4 * g + i) * RS + cout * 2) =
                        f2bf(kk.a[m][n][i] + kk.bia[n]);
            }
    }
    __syncthreads();

    // ---------------- t4: attention, one wave per head ----------------------
    {
        const int h = wave;
        short8 qa[4], kb[4];
        #pragma unroll
        for (int m = 0; m < 4; ++m)
            qa[m] = *(const short8*)(sm + O_HFQ + (16 * m + l15) * RS + (32 * h + 8 * g) * 2);
        #pragma unroll
        for (int n = 0; n < 4; ++n)
            kb[n] = *(const short8*)(sm + O_LNLF + (16 * n + l15) * RS + (32 * h + 8 * g) * 2);

        f32x4 z = {0.f, 0.f, 0.f, 0.f};
        f32x4 s[4][4];
        #pragma unroll
        for (int m = 0; m < 4; ++m)
            #pragma unroll
            for (int n = 0; n < 4; ++n)
                s[m][n] = mfma_bf16(qa[m], kb[n], z);

        // softmax over 64 keys per row; row r=16m+4g+i lives on the 16 lanes of group g
        #pragma unroll
        for (int m = 0; m < 4; ++m)
            #pragma unroll
            for (int i = 0; i < 4; ++i) {
                float mx = fmaxf(fmaxf(s[m][0][i], s[m][1][i]), fmaxf(s[m][2][i], s[m][3][i]));
                mx = fmaxf(mx, __shfl_xor(mx, 1));
                mx = fmaxf(mx, __shfl_xor(mx, 2));
                mx = fmaxf(mx, __shfl_xor(mx, 4));
                mx = fmaxf(mx, __shfl_xor(mx, 8));
                float e0 = __expf(s[m][0][i] - mx);
                float e1 = __expf(s[m][1][i] - mx);
                float e2 = __expf(s[m][2][i] - mx);
                float e3 = __expf(s[m][3][i] - mx);
                float sum = e0 + e1 + e2 + e3;
                sum += __shfl_xor(sum, 1);
                sum += __shfl_xor(sum, 2);
                sum += __shfl_xor(sum, 4);
                sum += __shfl_xor(sum, 8);
                float is = 1.f / sum;
                s[m][0][i] = e0 * is; s[m][1][i] = e1 * is;
                s[m][2][i] = e2 * is; s[m][3][i] = e3 * is;
            }

        // PV in two K-chunks of 32 keys via per-wave swizzled P scratch
        char* pbase = sm + O_LNHF + wave * 4096;
        f32x4 o[4][2];
        #pragma unroll
        for (int m = 0; m < 4; ++m) { o[m][0] = z; o[m][1] = z; }
        #pragma unroll
        for (int kk = 0; kk < 2; ++kk) {
            #pragma unroll
            for (int m = 0; m < 4; ++m)
                #pragma unroll
                for (int nn = 0; nn < 2; ++nn) {
                    int n = 2 * kk + nn;
                    int cl = l15 + 16 * nn;          // local key 0..31
                    int slot = cl >> 3;
                    #pragma unroll
                    for (int i = 0; i < 4; ++i) {
                        int row = 16 * m + 4 * g + i;
                        *(unsigned short*)(pbase + row * 64 + ((slot ^ (row & 3)) << 4) + (cl & 7) * 2) =
                            f2bf(s[m][n][i]);
                    }
                }
            short8 vb[2];
            #pragma unroll
            for (int n2 = 0; n2 < 2; ++n2)
                vb[n2] = *(const short8*)(sm + O_VT + (32 * h + 16 * n2 + l15) * 144 + (kk * 32 + 8 * g) * 2);
            #pragma unroll
            for (int m2 = 0; m2 < 4; ++m2) {
                int row = 16 * m2 + l15;
                short8 pa = *(const short8*)(pbase + row * 64 + ((g ^ (row & 3)) << 4));
                o[m2][0] = mfma_bf16(pa, vb[0], o[m2][0]);
                o[m2][1] = mfma_bf16(pa, vb[1], o[m2][1]);
            }
        }
        // O (this head's 32 channels) back into the Q region
        #pragma unroll
        for (int m2 = 0; m2 < 4; ++m2)
            #pragma unroll
            for (int n2 = 0; n2 < 2; ++n2) {
                int col = 32 * h + 16 * n2 + l15;
                #pragma unroll
                for (int i = 0; i < 4; ++i)
                    *(unsigned short*)(sm + O_HFQ + (16 * m2 + 4 * g + i) * RS + col * 2) = f2bf(o[m2][n2][i]);
            }
    }
    __syncthreads();

    // ---------------- t5: Out = O @ Wo^T + bo + hf, direct float4 stores ----
    {
        Acc42 oo = gemm64(sm, O_HFQ, Wo, bo, wave, g, l15);
        #pragma unroll
        for (int n = 0; n < 2; ++n) {
            int cout = 32 * wave + 16 * n + l15;
            #pragma unroll
            for (int m = 0; m < 4; ++m) {
                int tok0 = 16 * m + 4 * g;
                int ph = tok0 >> 3, pw = tok0 & 7;
                f4 ov;
                #pragma unroll
                for (int i = 0; i < 4; ++i)
                    ov[i] = oo.a[m][n][i] + oo.bia[n] + res[m][n][i];
                *(f4*)(out + win_base + (long)cout * HW + ph * W + pw) = ov;
            }
        }
    }
}

extern "C" void kernel_launch(void* const* d_in, const int* in_sizes, int n_in,
                              void* d_out, int out_size, void* d_ws, size_t ws_size,
                              hipStream_t stream) {
    (void)in_sizes; (void)n_in; (void)out_size; (void)d_ws; (void)ws_size;
    const float* y_lf = (const float*)d_in[0];
    const float* y_hf = (const float*)d_in[1];
    const float* g_lf = (const float*)d_in[2];
    const float* b_lf = (const float*)d_in[3];
    const float* g_hf = (const float*)d_in[4];
    const float* b_hf = (const float*)d_in[5];
    const float* Wq   = (const float*)d_in[6];
    const float* bq   = (const float*)d_in[7];
    const float* Wk   = (const float*)d_in[8];
    const float* bk   = (const float*)d_in[9];
    const float* Wv   = (const float*)d_in[10];
    const float* bv   = (const float*)d_in[11];
    const float* Wo   = (const float*)d_in[12];
    const float* bo   = (const float*)d_in[13];
    float* out = (float*)d_out;

    pcaf_kernel<<<dim3(4096), dim3(512), 0, stream>>>(
        y_lf, y_hf, g_lf, b_lf, g_hf, b_hf,
        Wq, bq, Wk, bk, Wv, bv, Wo, bo, out);
}

// Round 2
// 555.378 us; speedup vs baseline: 1.8448x; 1.8448x over previous
//
#include <hip/hip_runtime.h>

typedef float  f4     __attribute__((ext_vector_type(4)));
typedef float  f32x4  __attribute__((ext_vector_type(4)));
typedef short  short8 __attribute__((ext_vector_type(8)));
typedef __bf16 bf16x8 __attribute__((ext_vector_type(8)));
typedef unsigned short us4 __attribute__((ext_vector_type(4)));

__device__ __forceinline__ unsigned short f2bf(float f) {
    unsigned int u = __builtin_bit_cast(unsigned int, f);
    u += 0x7FFFu + ((u >> 16) & 1u);
    return (unsigned short)(u >> 16);
}
__device__ __forceinline__ float bf2f(unsigned short h) {
    unsigned int u = ((unsigned int)h) << 16;
    return __builtin_bit_cast(float, u);
}
__device__ __forceinline__ f32x4 mfma_bf16(short8 a, short8 b, f32x4 c) {
    return __builtin_amdgcn_mfma_f32_16x16x32_bf16(
        __builtin_bit_cast(bf16x8, a), __builtin_bit_cast(bf16x8, b), c, 0, 0, 0);
}

// ============================================================================
// Weight pre-conversion kernel: fold LayerNorm gamma into Wq/Wk, cvt to bf16.
// ws layout (bytes):
//   [0      .. 131071]  Wq' bf16 (Wq * g_lf broadcast over cin), row-major 256x256
//   [131072 .. 262143]  Wk' bf16 (Wk * g_hf)
//   [262144 .. 393215]  Wv  bf16
//   [393216 .. 524287]  Wo  bf16
//   [524288 .. 528383]  f32 consts: rowsum_q[256] | cbq[256] | rowsum_k[256] | cbk[256]
// ============================================================================
__global__ void pcaf_precvt(const float* __restrict__ Wq, const float* __restrict__ bq,
                            const float* __restrict__ Wk, const float* __restrict__ bk,
                            const float* __restrict__ Wv, const float* __restrict__ Wo,
                            const float* __restrict__ g_lf, const float* __restrict__ b_lf,
                            const float* __restrict__ g_hf, const float* __restrict__ b_hf,
                            void* __restrict__ ws) {
    const int mat  = blockIdx.x >> 8;      // 0=q 1=k 2=v 3=o
    const int row  = blockIdx.x & 255;
    const int lane = threadIdx.x;          // 0..63, 4 cin each
    const float* W = (mat == 0) ? Wq : (mat == 1) ? Wk : (mat == 2) ? Wv : Wo;
    f4 w = *(const f4*)(W + row * 256 + lane * 4);
    f4 wp = w;
    if (mat < 2) {
        const float* g = mat ? g_hf : g_lf;
        f4 gg = *(const f4*)(g + lane * 4);
        wp = w * gg;
    }
    us4 u;
    u[0] = f2bf(wp[0]); u[1] = f2bf(wp[1]); u[2] = f2bf(wp[2]); u[3] = f2bf(wp[3]);
    *(us4*)((unsigned short*)ws + mat * 65536 + row * 256 + lane * 4) = u;
    if (mat < 2) {
        const float* b = mat ? b_hf : b_lf;
        f4 bb = *(const f4*)(b + lane * 4);
        float rsum = wp[0] + wp[1] + wp[2] + wp[3];
        float cb   = bb[0] * w[0] + bb[1] * w[1] + bb[2] * w[2] + bb[3] * w[3];
        #pragma unroll
        for (int d = 1; d < 64; d <<= 1) {
            rsum += __shfl_xor(rsum, d);
            cb   += __shfl_xor(cb, d);
        }
        if (lane == 0) {
            float* cons = (float*)((char*)ws + 524288);
            cons[mat * 512 + row]       = rsum;
            cons[mat * 512 + 256 + row] = cb + (mat ? bk[row] : bq[row]);
        }
    }
}

// ============================================================================
// Main fused kernel: 1024 threads (16 waves), one window per block.
// ============================================================================
struct Acc4 { f32x4 a[4]; };

// 64x256 (tokens x cout-tile-of-16) GEMM slice; this wave owns cout0=16*wave+l15
__device__ __forceinline__ Acc4 gemm16(const char* sm, int off,
                                       const unsigned short* __restrict__ Wb,
                                       int cout0, int g, int l15) {
    short8 bw[8];
    #pragma unroll
    for (int k = 0; k < 8; ++k)
        bw[k] = *(const short8*)(Wb + cout0 * 256 + k * 32 + g * 8);
    Acc4 r;
    f32x4 z = {0.f, 0.f, 0.f, 0.f};
    #pragma unroll
    for (int m = 0; m < 4; ++m) r.a[m] = z;
    #pragma unroll
    for (int k = 0; k < 8; ++k) {
        #pragma unroll
        for (int m = 0; m < 4; ++m) {
            short8 am = *(const short8*)(sm + off + (16 * m + l15) * 528 + (k * 32 + g * 8) * 2);
            r.a[m] = mfma_bf16(am, bw[k], r.a[m]);
        }
    }
    return r;
}

__global__ __launch_bounds__(1024, 4) void pcaf2_kernel(
    const float* __restrict__ y_lf, const float* __restrict__ y_hf,
    const float* __restrict__ bv, const float* __restrict__ bo,
    const void* __restrict__ ws, float* __restrict__ out)
{
    constexpr int C = 256, H = 256, W = 256, HW = H * W;
    constexpr int RS = 528;
    constexpr int OA = 0;        // lf raw -> Q -> O          (33792)
    constexpr int OB = 33792;    // hf raw -> K               (33792)
    constexpr int OC = 67584;    // V^T [256][72] stride 144B (36864)
    constexpr int OD = 104448;   // per-wave P scratch 16x2KB (32768)
    constexpr int OS = 137216;   // stats: m_lf|r_lf|m_hf|r_hf (64 f32 each)
    __shared__ __align__(16) char sm[138240];

    const unsigned short* wsq = (const unsigned short*)ws;
    const unsigned short* wsk = wsq + 65536;
    const unsigned short* wsv = wsq + 131072;
    const unsigned short* wso = wsq + 196608;
    const float* cons = (const float*)((const char*)ws + 524288);

    const int tid = threadIdx.x;
    // XCD-aware swizzle: give each XCD a contiguous chunk of windows
    const int bid = blockIdx.x;
    const int wi  = ((bid & 7) << 9) | (bid >> 3);
    const int bb  = wi >> 10;
    const int nh  = (wi >> 5) & 31;
    const int nw  = wi & 31;
    const long win_base = (long)bb * C * HW + (long)(nh * 8) * W + nw * 8;

    const int wave = tid >> 6;      // 0..15
    const int lane = tid & 63;
    const int g    = lane >> 4;
    const int l15  = lane & 15;
    const int cout0 = 16 * wave + l15;

    // ---- P0: stage raw lf->A, hf->B as bf16 --------------------------------
    #pragma unroll
    for (int it = 0; it < 2; ++it) {
        int q2  = it * 1024 + tid;       // 0..2047
        int c2  = q2 >> 4;               // channel pair 0..127
        int ph  = (q2 >> 1) & 7;
        int pw4 = (q2 & 1) * 4;
        long go = win_base + (long)(2 * c2) * HW + ph * W + pw4;
        f4 l0 = *(const f4*)(y_lf + go);
        f4 l1 = *(const f4*)(y_lf + go + HW);
        f4 h0 = *(const f4*)(y_hf + go);
        f4 h1 = *(const f4*)(y_hf + go + HW);
        int tok0 = ph * 8 + pw4;
        #pragma unroll
        for (int j = 0; j < 4; ++j) {
            unsigned int lv = (unsigned int)f2bf(l0[j]) | ((unsigned int)f2bf(l1[j]) << 16);
            unsigned int hv = (unsigned int)f2bf(h0[j]) | ((unsigned int)f2bf(h1[j]) << 16);
            *(unsigned int*)(sm + OA + (tok0 + j) * RS + c2 * 4) = lv;
            *(unsigned int*)(sm + OB + (tok0 + j) * RS + c2 * 4) = hv;
        }
    }
    __syncthreads();   // BAR1

    // ---- P1: LN stats (both tensors) + residual->regs + Q GEMM -------------
    {
        const int half = tid >> 9;                 // 0: lf, 1: hf
        const int lt   = (tid & 511) >> 3;         // token
        const int j    = tid & 7;                  // 32-ch chunk
        const int base = half ? OB : OA;
        float sum = 0.f, ss = 0.f;
        #pragma unroll
        for (int r = 0; r < 4; ++r) {
            short8 raw = *(const short8*)(sm + base + lt * RS + (j * 32 + r * 8) * 2);
            #pragma unroll
            for (int e = 0; e < 8; ++e) { float f = bf2f((unsigned short)raw[e]); sum += f; ss += f * f; }
        }
        sum += __shfl_xor(sum, 1); ss += __shfl_xor(ss, 1);
        sum += __shfl_xor(sum, 2); ss += __shfl_xor(ss, 2);
        sum += __shfl_xor(sum, 4); ss += __shfl_xor(ss, 4);
        float mean = sum * (1.f / 256.f);
        float rstd = rsqrtf(ss * (1.f / 256.f) - mean * mean + 1e-5f);
        if (j == 0) {
            float* S = (float*)(sm + OS);
            S[half * 128 + lt]      = mean;
            S[half * 128 + 64 + lt] = rstd;
        }
    }
    float res[4][4];
    #pragma unroll
    for (int m = 0; m < 4; ++m)
        #pragma unroll
        for (int i = 0; i < 4; ++i)
            res[m][i] = bf2f(*(const unsigned short*)(sm + OB + (16 * m + 4 * g + i) * RS + cout0 * 2));

    Acc4 qacc = gemm16(sm, OA, wsq, cout0, g, l15);
    __syncthreads();   // BAR2 (all reads of A done)

    // ---- P1s: Q epilogue (LN folded) -> A ----------------------------------
    {
        const float* S = (const float*)(sm + OS);
        const float SCALE = 0.17677669529663687f;  // 1/sqrt(32)
        float rsq = cons[cout0], cbq = cons[256 + cout0];
        #pragma unroll
        for (int m = 0; m < 4; ++m)
            #pragma unroll
            for (int i = 0; i < 4; ++i) {
                int t = 16 * m + 4 * g + i;
                float val = (S[64 + t] * (qacc.a[m][i] - S[t] * rsq) + cbq) * SCALE;
                *(unsigned short*)(sm + OA + t * RS + cout0 * 2) = f2bf(val);
            }
    }

    // ---- P2: V GEMM from raw hf -> V^T in C --------------------------------
    {
        Acc4 vacc = gemm16(sm, OB, wsv, cout0, g, l15);
        float bvv = bv[cout0];
        #pragma unroll
        for (int m = 0; m < 4; ++m) {
            unsigned int p0 = (unsigned int)f2bf(vacc.a[m][0] + bvv) |
                              ((unsigned int)f2bf(vacc.a[m][1] + bvv) << 16);
            unsigned int p1 = (unsigned int)f2bf(vacc.a[m][2] + bvv) |
                              ((unsigned int)f2bf(vacc.a[m][3] + bvv) << 16);
            char* p = sm + OC + cout0 * 144 + (16 * m + 4 * g) * 2;
            *(unsigned int*)(p)     = p0;
            *(unsigned int*)(p + 4) = p1;
        }
    }

    // ---- P3: K GEMM from raw hf (LN folded) --------------------------------
    Acc4 kacc = gemm16(sm, OB, wsk, cout0, g, l15);
    __syncthreads();   // BAR3 (all reads of B done)
    {
        const float* S = (const float*)(sm + OS);
        float rsk = cons[512 + cout0], cbk = cons[768 + cout0];
        #pragma unroll
        for (int m = 0; m < 4; ++m)
            #pragma unroll
            for (int i = 0; i < 4; ++i) {
                int t = 16 * m + 4 * g + i;
                float val = S[192 + t] * (kacc.a[m][i] - S[128 + t] * rsk) + cbk;
                *(unsigned short*)(sm + OB + t * RS + cout0 * 2) = f2bf(val);
            }
    }
    __syncthreads();   // BAR4

    // ---- P4: attention; 2 waves per head, split by row-halves --------------
    {
        const int h    = wave >> 1;
        const int half = wave & 1;
        short8 qa[2], kb[4];
        #pragma unroll
        for (int mm = 0; mm < 2; ++mm)
            qa[mm] = *(const short8*)(sm + OA + (32 * half + 16 * mm + l15) * RS + (32 * h + 8 * g) * 2);
        #pragma unroll
        for (int n = 0; n < 4; ++n)
            kb[n] = *(const short8*)(sm + OB + (16 * n + l15) * RS + (32 * h + 8 * g) * 2);

        f32x4 z = {0.f, 0.f, 0.f, 0.f};
        f32x4 s[2][4];
        #pragma unroll
        for (int mm = 0; mm < 2; ++mm)
            #pragma unroll
            for (int n = 0; n < 4; ++n)
                s[mm][n] = mfma_bf16(qa[mm], kb[n], z);

        #pragma unroll
        for (int mm = 0; mm < 2; ++mm)
            #pragma unroll
            for (int i = 0; i < 4; ++i) {
                float mx = fmaxf(fmaxf(s[mm][0][i], s[mm][1][i]), fmaxf(s[mm][2][i], s[mm][3][i]));
                mx = fmaxf(mx, __shfl_xor(mx, 1));
                mx = fmaxf(mx, __shfl_xor(mx, 2));
                mx = fmaxf(mx, __shfl_xor(mx, 4));
                mx = fmaxf(mx, __shfl_xor(mx, 8));
                float e0 = __expf(s[mm][0][i] - mx);
                float e1 = __expf(s[mm][1][i] - mx);
                float e2 = __expf(s[mm][2][i] - mx);
                float e3 = __expf(s[mm][3][i] - mx);
                float sum = e0 + e1 + e2 + e3;
                sum += __shfl_xor(sum, 1);
                sum += __shfl_xor(sum, 2);
                sum += __shfl_xor(sum, 4);
                sum += __shfl_xor(sum, 8);
                float is = 1.f / sum;
                s[mm][0][i] = e0 * is; s[mm][1][i] = e1 * is;
                s[mm][2][i] = e2 * is; s[mm][3][i] = e3 * is;
            }

        char* pbase = sm + OD + wave * 2048;
        f32x4 o[2][2];
        o[0][0] = z; o[0][1] = z; o[1][0] = z; o[1][1] = z;
        #pragma unroll
        for (int kk = 0; kk < 2; ++kk) {
            #pragma unroll
            for (int mm = 0; mm < 2; ++mm)
                #pragma unroll
                for (int nn = 0; nn < 2; ++nn) {
                    int n = 2 * kk + nn;
                    int cl = l15 + 16 * nn;
                    int slot = cl >> 3;
                    #pragma unroll
                    for (int i = 0; i < 4; ++i) {
                        int lr = 16 * mm + 4 * g + i;
                        *(unsigned short*)(pbase + lr * 64 + ((slot ^ (lr & 3)) << 4) + (cl & 7) * 2) =
                            f2bf(s[mm][n][i]);
                    }
                }
            short8 vb[2];
            #pragma unroll
            for (int n2 = 0; n2 < 2; ++n2)
                vb[n2] = *(const short8*)(sm + OC + (32 * h + 16 * n2 + l15) * 144 + (kk * 32 + 8 * g) * 2);
            #pragma unroll
            for (int mm2 = 0; mm2 < 2; ++mm2) {
                int lr2 = 16 * mm2 + l15;
                short8 pa = *(const short8*)(pbase + lr2 * 64 + ((g ^ (lr2 & 3)) << 4));
                o[mm2][0] = mfma_bf16(pa, vb[0], o[mm2][0]);
                o[mm2][1] = mfma_bf16(pa, vb[1], o[mm2][1]);
            }
        }
        #pragma unroll
        for (int mm2 = 0; mm2 < 2; ++mm2)
            #pragma unroll
            for (int n2 = 0; n2 < 2; ++n2) {
                int col = 32 * h + 16 * n2 + l15;
                #pragma unroll
                for (int i = 0; i < 4; ++i) {
                    int row = 32 * half + 16 * mm2 + 4 * g + i;
                    *(unsigned short*)(sm + OA + row * RS + col * 2) = f2bf(o[mm2][n2][i]);
                }
            }
    }
    __syncthreads();   // BAR5

    // ---- P5: out-proj + residual, direct float4 stores ---------------------
    {
        Acc4 oacc = gemm16(sm, OA, wso, cout0, g, l15);
        float bov = bo[cout0];
        #pragma unroll
        for (int m = 0; m < 4; ++m) {
            int tok0 = 16 * m + 4 * g;
            int ph = tok0 >> 3, pw = tok0 & 7;
            f4 ov;
            #pragma unroll
            for (int i = 0; i < 4; ++i)
                ov[i] = oacc.a[m][i] + bov + res[m][i];
            *(f4*)(out + win_base + (long)cout0 * HW + ph * W + pw) = ov;
        }
    }
}

// ============================================================================
// Fallback (round-1 kernel, self-contained) if ws is too small.
// ============================================================================
struct Acc42 { f32x4 a[4][2]; float bia[2]; };

__device__ __forceinline__ Acc42 gemm64(char* sm, int src_off,
                                        const float* __restrict__ Wm,
                                        const float* __restrict__ bias,
                                        int wave, int g, int l15) {
    short8 bw[2][8];
    const int cout0 = 32 * wave + l15;
    #pragma unroll
    for (int n = 0; n < 2; ++n) {
        const float* wp = Wm + (cout0 + 16 * n) * 256 + g * 8;
        #pragma unroll
        for (int k = 0; k < 8; ++k) {
            f4 w0 = *(const f4*)(wp + k * 32);
            f4 w1 = *(const f4*)(wp + k * 32 + 4);
            short8 t;
            t[0] = (short)f2bf(w0[0]); t[1] = (short)f2bf(w0[1]);
            t[2] = (short)f2bf(w0[2]); t[3] = (short)f2bf(w0[3]);
            t[4] = (short)f2bf(w1[0]); t[5] = (short)f2bf(w1[1]);
            t[6] = (short)f2bf(w1[2]); t[7] = (short)f2bf(w1[3]);
            bw[n][k] = t;
        }
    }
    Acc42 r;
    f32x4 z = {0.f, 0.f, 0.f, 0.f};
    #pragma unroll
    for (int m = 0; m < 4; ++m) { r.a[m][0] = z; r.a[m][1] = z; }
    #pragma unroll
    for (int k = 0; k < 8; ++k) {
        #pragma unroll
        for (int m = 0; m < 4; ++m) {
            short8 am = *(const short8*)(sm + src_off + (16 * m + l15) * 528 + (k * 32 + g * 8) * 2);
            r.a[m][0] = mfma_bf16(am, bw[0][k], r.a[m][0]);
            r.a[m][1] = mfma_bf16(am, bw[1][k], r.a[m][1]);
        }
    }
    r.bia[0] = bias[cout0];
    r.bia[1] = bias[cout0 + 16];
    return r;
}

__global__ __launch_bounds__(512, 2) void pcaf_kernel(
    const float* __restrict__ y_lf, const float* __restrict__ y_hf,
    const float* __restrict__ g_lf, const float* __restrict__ b_lf,
    const float* __restrict__ g_hf, const float* __restrict__ b_hf,
    const float* __restrict__ Wq, const float* __restrict__ bq,
    const float* __restrict__ Wk, const float* __restrict__ bk,
    const float* __restrict__ Wv, const float* __restrict__ bv,
    const float* __restrict__ Wo, const float* __restrict__ bo,
    float* __restrict__ out)
{
    constexpr int C = 256, H = 256, W = 256, HW = H * W;
    constexpr int RS = 528;
    constexpr int O_LNLF = 0;
    constexpr int O_LNHF = 33792;
    constexpr int O_HFQ  = 67584;
    constexpr int O_VT   = 101376;
    constexpr int O_GB   = 138240;
    __shared__ __align__(16) char sm[142336];

    const int tid  = threadIdx.x;
    const int wi   = blockIdx.x;
    const int bb   = wi >> 10;
    const int nh   = (wi >> 5) & 31;
    const int nw   = wi & 31;
    const long win_base = (long)bb * C * HW + (long)(nh * 8) * W + nw * 8;

    const int wave = tid >> 6;
    const int lane = tid & 63;
    const int g    = lane >> 4;
    const int l15  = lane & 15;

    if (tid < 256) {
        float* gbp = (float*)(sm + O_GB);
        gbp[tid]       = g_lf[tid];
        gbp[256 + tid] = b_lf[tid];
        gbp[512 + tid] = g_hf[tid];
        gbp[768 + tid] = b_hf[tid];
    }
    #pragma unroll
    for (int it = 0; it < 4; ++it) {
        int q2  = it * 512 + tid;
        int c2  = q2 >> 4;
        int ph  = (q2 >> 1) & 7;
        int pw4 = (q2 & 1) * 4;
        long go = win_base + (long)(2 * c2) * HW + ph * W + pw4;
        f4 l0 = *(const f4*)(y_lf + go);
        f4 l1 = *(const f4*)(y_lf + go + HW);
        f4 h0 = *(const f4*)(y_hf + go);
        f4 h1 = *(const f4*)(y_hf + go + HW);
        int tok0 = ph * 8 + pw4;
        #pragma unroll
        for (int j = 0; j < 4; ++j) {
            unsigned int lv = (unsigned int)f2bf(l0[j]) | ((unsigned int)f2bf(l1[j]) << 16);
            unsigned int hv = (unsigned int)f2bf(h0[j]) | ((unsigned int)f2bf(h1[j]) << 16);
            *(unsigned int*)(sm + O_LNLF + (tok0 + j) * RS + c2 * 4) = lv;
            *(unsigned int*)(sm + O_HFQ  + (tok0 + j) * RS + c2 * 4) = hv;
        }
    }
    __syncthreads();

    {
        const int t = tid >> 3, j = tid & 7;
        const float* gbp = (const float*)(sm + O_GB);
        {
            short8 raw[4];
            float sum = 0.f, ss = 0.f;
            #pragma unroll
            for (int r = 0; r < 4; ++r) {
                raw[r] = *(const short8*)(sm + O_LNLF + t * RS + (j * 32 + r * 8) * 2);
                #pragma unroll
                for (int e = 0; e < 8; ++e) { float f = bf2f((unsigned short)raw[r][e]); sum += f; ss += f * f; }
            }
            sum += __shfl_xor(sum, 1); ss += __shfl_xor(ss, 1);
            sum += __shfl_xor(sum, 2); ss += __shfl_xor(ss, 2);
            sum += __shfl_xor(sum, 4); ss += __shfl_xor(ss, 4);
            float mean = sum * (1.f / 256.f);
            float rstd = rsqrtf(ss * (1.f / 256.f) - mean * mean + 1e-5f);
            #pragma unroll
            for (int r = 0; r < 4; ++r) {
                short8 o;
                #pragma unroll
                for (int e = 0; e < 8; ++e) {
                    int c = j * 32 + r * 8 + e;
                    float f = (bf2f((unsigned short)raw[r][e]) - mean) * rstd * gbp[c] + gbp[256 + c];
                    o[e] = (short)f2bf(f);
                }
                *(short8*)(sm + O_LNLF + t * RS + (j * 32 + r * 8) * 2) = o;
            }
        }
        {
            short8 raw[4];
            float sum = 0.f, ss = 0.f;
            #pragma unroll
            for (int r = 0; r < 4; ++r) {
                raw[r] = *(const short8*)(sm + O_HFQ + t * RS + (j * 32 + r * 8) * 2);
                #pragma unroll
                for (int e = 0; e < 8; ++e) { float f = bf2f((unsigned short)raw[r][e]); sum += f; ss += f * f; }
            }
            sum += __shfl_xor(sum, 1); ss += __shfl_xor(ss, 1);
            sum += __shfl_xor(sum, 2); ss += __shfl_xor(ss, 2);
            sum += __shfl_xor(sum, 4); ss += __shfl_xor(ss, 4);
            float mean = sum * (1.f / 256.f);
            float rstd = rsqrtf(ss * (1.f / 256.f) - mean * mean + 1e-5f);
            #pragma unroll
            for (int r = 0; r < 4; ++r) {
                short8 o;
                #pragma unroll
                for (int e = 0; e < 8; ++e) {
                    int c = j * 32 + r * 8 + e;
                    float f = (bf2f((unsigned short)raw[r][e]) - mean) * rstd * gbp[512 + c] + gbp[768 + c];
                    o[e] = (short)f2bf(f);
                }
                *(short8*)(sm + O_LNHF + t * RS + (j * 32 + r * 8) * 2) = o;
            }
        }
    }
    __syncthreads();

    float res[4][2][4];
    #pragma unroll
    for (int m = 0; m < 4; ++m)
        #pragma unroll
        for (int n = 0; n < 2; ++n) {
            int col = 32 * wave + 16 * n + l15;
            #pragma unroll
            for (int i = 0; i < 4; ++i)
                res[m][n][i] = bf2f(*(const unsigned short*)(sm + O_HFQ + (16 * m + 4 * g + i) * RS + col * 2));
        }
    {
        Acc42 v = gemm64(sm, O_HFQ, Wv, bv, wave, g, l15);
        #pragma unroll
        for (int m = 0; m < 4; ++m)
            #pragma unroll
            for (int n = 0; n < 2; ++n) {
                int cout = 32 * wave + 16 * n + l15;
                unsigned int p0 = (unsigned int)f2bf(v.a[m][n][0] + v.bia[n]) |
                                  ((unsigned int)f2bf(v.a[m][n][1] + v.bia[n]) << 16);
                unsigned int p1 = (unsigned int)f2bf(v.a[m][n][2] + v.bia[n]) |
                                  ((unsigned int)f2bf(v.a[m][n][3] + v.bia[n]) << 16);
                char* p = sm + O_VT + cout * 144 + (16 * m + 4 * g) * 2;
                *(unsigned int*)(p)     = p0;
                *(unsigned int*)(p + 4) = p1;
            }
    }
    __syncthreads();

    {
        Acc42 q = gemm64(sm, O_LNLF, Wq, bq, wave, g, l15);
        const float SCALE = 0.17677669529663687f;
        #pragma unroll
        for (int m = 0; m < 4; ++m)
            #pragma unroll
            for (int n = 0; n < 2; ++n) {
                int cout = 32 * wave + 16 * n + l15;
                #pragma unroll
                for (int i = 0; i < 4; ++i) {
                    float val = (q.a[m][n][i] + q.bia[n]) * SCALE;
                    *(unsigned short*)(sm + O_HFQ + (16 * m + 4 * g + i) * RS + cout * 2) = f2bf(val);
                }
            }
    }
    __syncthreads();

    {
        Acc42 kk = gemm64(sm, O_LNHF, Wk, bk, wave, g, l15);
        #pragma unroll
        for (int m = 0; m < 4; ++m)
            #pragma unroll
            for (int n = 0; n < 2; ++n) {
                int cout = 32 * wave + 16 * n + l15;
                #pragma unroll
                for (int i = 0; i < 4; ++i)
                    *(unsigned short*)(sm + O_LNLF + (16 * m + 4 * g + i) * RS + cout * 2) =
                        f2bf(kk.a[m][n][i] + kk.bia[n]);
            }
    }
    __syncthreads();

    {
        const int h = wave;
        short8 qa[4], kb[4];
        #pragma unroll
        for (int m = 0; m < 4; ++m)
            qa[m] = *(const short8*)(sm + O_HFQ + (16 * m + l15) * RS + (32 * h + 8 * g) * 2);
        #pragma unroll
        for (int n = 0; n < 4; ++n)
            kb[n] = *(const short8*)(sm + O_LNLF + (16 * n + l15) * RS + (32 * h + 8 * g) * 2);

        f32x4 z = {0.f, 0.f, 0.f, 0.f};
        f32x4 s[4][4];
        #pragma unroll
        for (int m = 0; m < 4; ++m)
            #pragma unroll
            for (int n = 0; n < 4; ++n)
                s[m][n] = mfma_bf16(qa[m], kb[n], z);

        #pragma unroll
        for (int m = 0; m < 4; ++m)
            #pragma unroll
            for (int i = 0; i < 4; ++i) {
                float mx = fmaxf(fmaxf(s[m][0][i], s[m][1][i]), fmaxf(s[m][2][i], s[m][3][i]));
                mx = fmaxf(mx, __shfl_xor(mx, 1));
                mx = fmaxf(mx, __shfl_xor(mx, 2));
                mx = fmaxf(mx, __shfl_xor(mx, 4));
                mx = fmaxf(mx, __shfl_xor(mx, 8));
                float e0 = __expf(s[m][0][i] - mx);
                float e1 = __expf(s[m][1][i] - mx);
                float e2 = __expf(s[m][2][i] - mx);
                float e3 = __expf(s[m][3][i] - mx);
                float sum = e0 + e1 + e2 + e3;
                sum += __shfl_xor(sum, 1);
                sum += __shfl_xor(sum, 2);
                sum += __shfl_xor(sum, 4);
                sum += __shfl_xor(sum, 8);
                float is = 1.f / sum;
                s[m][0][i] = e0 * is; s[m][1][i] = e1 * is;
                s[m][2][i] = e2 * is; s[m][3][i] = e3 * is;
            }

        char* pbase = sm + O_LNHF + wave * 4096;
        f32x4 o[4][2];
        #pragma unroll
        for (int m = 0; m < 4; ++m) { o[m][0] = z; o[m][1] = z; }
        #pragma unroll
        for (int kk = 0; kk < 2; ++kk) {
            #pragma unroll
            for (int m = 0; m < 4; ++m)
                #pragma unroll
                for (int nn = 0; nn < 2; ++nn) {
                    int n = 2 * kk + nn;
                    int cl = l15 + 16 * nn;
                    int slot = cl >> 3;
                    #pragma unroll
                    for (int i = 0; i < 4; ++i) {
                        int row = 16 * m + 4 * g + i;
                        *(unsigned short*)(pbase + row * 64 + ((slot ^ (row & 3)) << 4) + (cl & 7) * 2) =
                            f2bf(s[m][n][i]);
                    }
                }
            short8 vb[2];
            #pragma unroll
            for (int n2 = 0; n2 < 2; ++n2)
                vb[n2] = *(const short8*)(sm + O_VT + (32 * h + 16 * n2 + l15) * 144 + (kk * 32 + 8 * g) * 2);
            #pragma unroll
            for (int m2 = 0; m2 < 4; ++m2) {
                int row = 16 * m2 + l15;
                short8 pa = *(const short8*)(pbase + row * 64 + ((g ^ (row & 3)) << 4));
                o[m2][0] = mfma_bf16(pa, vb[0], o[m2][0]);
                o[m2][1] = mfma_bf16(pa, vb[1], o[m2][1]);
            }
        }
        #pragma unroll
        for (int m2 = 0; m2 < 4; ++m2)
            #pragma unroll
            for (int n2 = 0; n2 < 2; ++n2) {
                int col = 32 * h + 16 * n2 + l15;
                #pragma unroll
                for (int i = 0; i < 4; ++i)
                    *(unsigned short*)(sm + O_HFQ + (16 * m2 + 4 * g + i) * RS + col * 2) = f2bf(o[m2][n2][i]);
            }
    }
    __syncthreads();

    {
        Acc42 oo = gemm64(sm, O_HFQ, Wo, bo, wave, g, l15);
        #pragma unroll
        for (int n = 0; n < 2; ++n) {
            int cout = 32 * wave + 16 * n + l15;
            #pragma unroll
            for (int m = 0; m < 4; ++m) {
                int tok0 = 16 * m + 4 * g;
                int ph = tok0 >> 3, pw = tok0 & 7;
                f4 ov;
                #pragma unroll
                for (int i = 0; i < 4; ++i)
                    ov[i] = oo.a[m][n][i] + oo.bia[n] + res[m][n][i];
                *(f4*)(out + win_base + (long)cout * HW + ph * W + pw) = ov;
            }
        }
    }
}

extern "C" void kernel_launch(void* const* d_in, const int* in_sizes, int n_in,
                              void* d_out, int out_size, void* d_ws, size_t ws_size,
                              hipStream_t stream) {
    (void)in_sizes; (void)n_in; (void)out_size;
    const float* y_lf = (const float*)d_in[0];
    const float* y_hf = (const float*)d_in[1];
    const float* g_lf = (const float*)d_in[2];
    const float* b_lf = (const float*)d_in[3];
    const float* g_hf = (const float*)d_in[4];
    const float* b_hf = (const float*)d_in[5];
    const float* Wq   = (const float*)d_in[6];
    const float* bq   = (const float*)d_in[7];
    const float* Wk   = (const float*)d_in[8];
    const float* bk   = (const float*)d_in[9];
    const float* Wv   = (const float*)d_in[10];
    const float* bv   = (const float*)d_in[11];
    const float* Wo   = (const float*)d_in[12];
    const float* bo   = (const float*)d_in[13];
    float* out = (float*)d_out;

    const size_t WS_NEED = 524288 + 4096;
    if (ws_size >= WS_NEED) {
        pcaf_precvt<<<dim3(1024), dim3(64), 0, stream>>>(
            Wq, bq, Wk, bk, Wv, Wo, g_lf, b_lf, g_hf, b_hf, d_ws);
        pcaf2_kernel<<<dim3(4096), dim3(1024), 0, stream>>>(
            y_lf, y_hf, bv, bo, d_ws, out);
    } else {
        pcaf_kernel<<<dim3(4096), dim3(512), 0, stream>>>(
            y_lf, y_hf, g_lf, b_lf, g_hf, b_hf,
            Wq, bq, Wk, bk, Wv, bv, Wo, bo, out);
    }
}